// Round 7
// baseline (346.294 us; speedup 1.0000x reference)
//
#include <hip/hip_runtime.h>
#include <hip/hip_bf16.h>
#include <math.h>

typedef unsigned short u16;
typedef __bf16 bf16x8_t __attribute__((ext_vector_type(8)));
typedef u16 u16x8 __attribute__((ext_vector_type(8)));
typedef float f32x4 __attribute__((ext_vector_type(4)));

#define NH 12
#define LQ 2048
#define DM 768
#define DH 64
#define NR 4095           // 2L-1
#define LN2F 0.6931471805599453f

__device__ __forceinline__ u16 f2bf(float f){
  unsigned x = __float_as_uint(f);
  return (u16)((x + 0x7fffu + ((x >> 16) & 1u)) >> 16);   // RTNE
}
__device__ __forceinline__ float bf2f(u16 u){ return __uint_as_float(((unsigned)u) << 16); }

__device__ __forceinline__ f32x4 MFMA(u16x8 a, u16x8 b, f32x4 c){
  return __builtin_amdgcn_mfma_f32_16x16x32_bf16(
      __builtin_bit_cast(bf16x8_t, a), __builtin_bit_cast(bf16x8_t, b), c, 0, 0, 0);
}

// ---------------- gamma pdf table (unnormalized) + global max ----------------
// conc=4(f+1)^2, rate=(f+1)/4 exact; f64 vs catastrophic cancellation.
// xlogy(conc-1,0)=0 -> p(x=0)=exp(conc*log(rate)-lgamma(conc)) nonzero.
__global__ void gamma_probs_kernel(float* __restrict__ gamtab,
                                   unsigned long long* __restrict__ gmax){
  int idx = blockIdx.x * 256 + threadIdx.x;   // 2048*128
  int x = idx >> 7, f = idx & 127;
  double fp1 = (double)(f + 1);
  double conc = 4.0 * fp1 * fp1;
  double rate = 0.25 * fp1;
  double xd = (double)x;
  double xlogy = (x > 0) ? (conc - 1.0) * log(xd) : 0.0;
  double logp = xlogy - rate * xd - lgamma(conc) + conc * log(rate);
  double p = exp(logp);
  gamtab[idx] = (float)p;
  double m = p;
  #pragma unroll
  for (int off = 1; off < 64; off <<= 1) m = fmax(m, __shfl_xor(m, off));
  if ((threadIdx.x & 63) == 0)
    atomicMax(gmax, (unsigned long long)__double_as_longlong(m));  // p>=0: bits monotone
}

// ---------------- positional encodings pe[4095][768] ----------------
__global__ void pe_kernel(const float* __restrict__ gamtab,
                          const unsigned long long* __restrict__ gmax,
                          float* __restrict__ pe){
  int idx = blockIdx.x * 256 + threadIdx.x;
  if (idx >= NR * DM) return;
  int p = idx / DM;
  int c = idx - p * DM;
  int f = c & 127;
  int kind = c >> 7;                 // 0:exp 1:exp*sgn 2:cm 3:cm*sgn 4:gam 5:gam*sgn
  int pos = p - (LQ - 1);
  int apos = pos < 0 ? -pos : pos;
  float sgn = (pos > 0) ? 1.f : ((pos < 0) ? -1.f : 0.f);
  float v;
  int grp = kind >> 1;
  if (grp == 0){
    float hl = exp2f(3.f + 8.f * (float)f / 127.f);
    v = expf(-(LN2F / hl) * (float)apos);
  } else if (grp == 1){
    float cw = exp2f((float)(f + 1)) - 1.f;
    v = (cw > (float)apos) ? 1.f : 0.f;
  } else {
    float gm = (float)__longlong_as_double((long long)*gmax);
    v = gamtab[apos * 128 + f] / gm;
  }
  if (kind & 1) v *= sgn;
  pe[idx] = v;
}

// ---------------- generic bf16-MFMA GEMM: C[M,768] = A[M,768] @ W[768,768] ----
// mode 0: out bf16 head-major  outb[((n>>6)*M + m)*64 + (n&63)], *scale
// mode 1: out f32 flat outf[m*768+n] = acc + bias[n]   (final output 0)
#define GSTR 56   // LDS row stride (elems): 112B, 16B-aligned
__launch_bounds__(256)
__global__ void gemm_kernel(const float* __restrict__ A, const float* __restrict__ W,
                            u16* __restrict__ outb, float* __restrict__ outf,
                            int M, float scale,
                            const float* __restrict__ bias, int mode){
  __shared__ u16 At[64 * GSTR];
  __shared__ u16 Wt[64 * GSTR];
  const int m0 = blockIdx.x * 64, n0 = blockIdx.y * 64;
  const int tid = threadIdx.x;
  const int w = tid >> 6, l = tid & 63, lr = l & 15, lg = l >> 4;
  const int moff = (w & 1) * 32, noff = (w >> 1) * 32;
  f32x4 acc[2][2] = {};
  const int arow = tid >> 2, akg = (tid & 3) * 8;
  const int wn = tid & 63, wkg = (tid >> 6) * 8;
  for (int k0 = 0; k0 < DM; k0 += 32){
    u16x8 av;
    if (m0 + arow < M){
      const float* ap = A + (size_t)(m0 + arow) * DM + k0 + akg;
      #pragma unroll
      for (int j = 0; j < 8; j++) av[j] = f2bf(ap[j]);
    } else {
      #pragma unroll
      for (int j = 0; j < 8; j++) av[j] = 0;
    }
    *(u16x8*)&At[arow * GSTR + akg] = av;
    u16x8 wv;
    #pragma unroll
    for (int i = 0; i < 8; i++)
      wv[i] = f2bf(W[(size_t)(k0 + wkg + i) * DM + n0 + wn]);
    *(u16x8*)&Wt[wn * GSTR + wkg] = wv;    // transposed stage: Wt[n][k]
    __syncthreads();
    u16x8 af0 = *(u16x8*)&At[(moff + lr) * GSTR + lg * 8];
    u16x8 af1 = *(u16x8*)&At[(moff + 16 + lr) * GSTR + lg * 8];
    u16x8 bf0 = *(u16x8*)&Wt[(noff + lr) * GSTR + lg * 8];
    u16x8 bf1 = *(u16x8*)&Wt[(noff + 16 + lr) * GSTR + lg * 8];
    acc[0][0] = MFMA(af0, bf0, acc[0][0]);
    acc[0][1] = MFMA(af0, bf1, acc[0][1]);
    acc[1][0] = MFMA(af1, bf0, acc[1][0]);
    acc[1][1] = MFMA(af1, bf1, acc[1][1]);
    __syncthreads();
  }
  #pragma unroll
  for (int mi = 0; mi < 2; mi++)
    #pragma unroll
    for (int ni = 0; ni < 2; ni++)
      #pragma unroll
      for (int j = 0; j < 4; j++){
        int m = m0 + moff + mi * 16 + lg * 4 + j;
        int n = n0 + noff + ni * 16 + lr;
        if (m < M){
          float v = acc[mi][ni][j] * scale;
          if (mode == 1){
            outf[(size_t)m * DM + n] = v + bias[n];
          } else {
            outb[((size_t)(n >> 6) * M + m) * DH + (n & 63)] = f2bf(v);
          }
        }
      }
}

// ---------------- V transpose: vt[h][d][k] = vh[h][k][d] (bf16) ----------------
__global__ void transpose_v_kernel(const u16* __restrict__ vh, u16* __restrict__ vt){
  __shared__ u16 tile[64 * 72];
  const int h = blockIdx.y, k0 = blockIdx.x * 64;
  const int t = threadIdx.x;
  {
    int kr = t >> 2, dg = (t & 3) * 16;
    const u16* p = vh + (size_t)(h * LQ + k0 + kr) * DH + dg;
    *(u16x8*)&tile[kr * 72 + dg]     = *(const u16x8*)p;
    *(u16x8*)&tile[kr * 72 + dg + 8] = *(const u16x8*)(p + 8);
  }
  __syncthreads();
  {
    int d = t >> 2, kg = (t & 3) * 16;
    u16x8 o0, o1;
    #pragma unroll
    for (int j = 0; j < 8; j++){
      o0[j] = tile[(kg + j) * 72 + d];
      o1[j] = tile[(kg + j + 8) * 72 + d];
    }
    u16* qp = vt + (size_t)(h * DH + d) * LQ + k0 + kg;
    *(u16x8*)qp = o0;
    *(u16x8*)(qp + 8) = o1;
  }
}

// ---------------- fused rel-pos attention ----------------
// One WG = 1 head x 32 q-rows, 8 waves; wave w owns k-slice [w*256, w*256+256).
// LDS band RP[32][2184] bf16 holds R (rel band), later P. S stays in regs.
// map (output 1) written as f32.
#define RPSTR 2184
#define SMEM_ATTN (32 * RPSTR * 2 + 2048)
__launch_bounds__(512)
__global__ void attn_kernel(const u16* __restrict__ qh, const u16* __restrict__ kh,
                            const u16* __restrict__ vt, const u16* __restrict__ rk,
                            const int* __restrict__ mask,
                            const float* __restrict__ r_w, const float* __restrict__ r_r,
                            float* __restrict__ map, float* __restrict__ att){
  extern __shared__ char smem[];
  u16* RP = (u16*)smem;
  float* redm = (float*)(smem + 32 * RPSTR * 2);   // [8][32]
  float* redl = redm + 256;                        // [8][32]
  const int h = blockIdx.y, q0 = blockIdx.x * 32;
  const int tid = threadIdx.x, w = tid >> 6, l = tid & 63, lr = l & 15, lg = l >> 4;
  const int roff = 2016 - q0;   // 2047 - q0 - 31

  // phase 0: A fragments a1=(qh+r_w), a2=(qh+r_r)  (qh pre-scaled by 1/8)
  u16x8 a1[2][2], a2[2][2];
  #pragma unroll
  for (int kc = 0; kc < 2; kc++){
    float rw8[8], rr8[8];
    #pragma unroll
    for (int j = 0; j < 8; j++){
      int d = kc * 32 + lg * 8 + j;
      rw8[j] = r_w[h * DH + d];
      rr8[j] = r_r[h * DH + d];
    }
    #pragma unroll
    for (int mi = 0; mi < 2; mi++){
      u16x8 qv = *(const u16x8*)(qh + (size_t)(h * LQ + q0 + mi * 16 + lr) * DH + kc * 32 + lg * 8);
      #pragma unroll
      for (int j = 0; j < 8; j++){
        float f = bf2f(qv[j]);
        a1[mi][kc][j] = f2bf(f + rw8[j]);
        a2[mi][kc][j] = f2bf(f + rr8[j]);
      }
    }
  }

  // phase 1: rel band R[q][j] = a2[q] . rk[roff + j]
  const int jb = w * 272;
  #pragma unroll 4
  for (int jt = 0; jt < 17; jt++){
    f32x4 racc[2] = {};
    #pragma unroll
    for (int kc = 0; kc < 2; kc++){
      int r = roff + jb + jt * 16 + lr;
      if (r > NR - 1) r = NR - 1;     // clamped tail never gathered
      u16x8 bv = *(const u16x8*)(rk + (size_t)(h * NR + r) * DH + kc * 32 + lg * 8);
      racc[0] = MFMA(a2[0][kc], bv, racc[0]);
      racc[1] = MFMA(a2[1][kc], bv, racc[1]);
    }
    #pragma unroll
    for (int mi = 0; mi < 2; mi++)
      #pragma unroll
      for (int j = 0; j < 4; j++)
        RP[(mi * 16 + lg * 4 + j) * RPSTR + jb + jt * 16 + lr] = f2bf(racc[mi][j]);
  }
  __syncthreads();

  // phase 2: content logits + gathered rel (j = k + 31 - q_local) + mask
  const int kb = w * 256;
  f32x4 s[2][16] = {};
  #pragma unroll
  for (int nt = 0; nt < 16; nt++){
    #pragma unroll
    for (int kc = 0; kc < 2; kc++){
      u16x8 bv = *(const u16x8*)(kh + (size_t)(h * LQ + kb + nt * 16 + lr) * DH + kc * 32 + lg * 8);
      s[0][nt] = MFMA(a1[0][kc], bv, s[0][nt]);
      s[1][nt] = MFMA(a1[1][kc], bv, s[1][nt]);
    }
  }
  #pragma unroll
  for (int nt = 0; nt < 16; nt++){
    int kg = kb + nt * 16 + lr;
    int mv = mask[kg];
    #pragma unroll
    for (int mi = 0; mi < 2; mi++)
      #pragma unroll
      for (int j = 0; j < 4; j++){
        int ql = mi * 16 + lg * 4 + j;
        float sv = s[mi][nt][j] + bf2f(RP[ql * RPSTR + kg + 31 - ql]);
        s[mi][nt][j] = (mv == 1) ? -10000.f : sv;
      }
  }

  // phase 3: exact softmax
  float fm[2][4], inv[2][4], lsum[2][4];
  #pragma unroll
  for (int mi = 0; mi < 2; mi++)
    #pragma unroll
    for (int j = 0; j < 4; j++){
      float mx = -3.0e38f;
      #pragma unroll
      for (int nt = 0; nt < 16; nt++) mx = fmaxf(mx, s[mi][nt][j]);
      #pragma unroll
      for (int off = 1; off < 16; off <<= 1) mx = fmaxf(mx, __shfl_xor(mx, off));
      if (lr == 0) redm[w * 32 + mi * 16 + lg * 4 + j] = mx;
    }
  __syncthreads();
  #pragma unroll
  for (int mi = 0; mi < 2; mi++)
    #pragma unroll
    for (int j = 0; j < 4; j++){
      int ql = mi * 16 + lg * 4 + j;
      float mx = redm[ql];
      #pragma unroll
      for (int w2 = 1; w2 < 8; w2++) mx = fmaxf(mx, redm[w2 * 32 + ql]);
      fm[mi][j] = mx;
      lsum[mi][j] = 0.f;
    }
  #pragma unroll
  for (int nt = 0; nt < 16; nt++)
    #pragma unroll
    for (int mi = 0; mi < 2; mi++)
      #pragma unroll
      for (int j = 0; j < 4; j++){
        float p = __expf(s[mi][nt][j] - fm[mi][j]);
        s[mi][nt][j] = p;
        lsum[mi][j] += p;
        RP[(mi * 16 + lg * 4 + j) * RPSTR + kb + nt * 16 + lr] = f2bf(p);  // P overwrites R
      }
  #pragma unroll
  for (int mi = 0; mi < 2; mi++)
    #pragma unroll
    for (int j = 0; j < 4; j++){
      float ls = lsum[mi][j];
      #pragma unroll
      for (int off = 1; off < 16; off <<= 1) ls += __shfl_xor(ls, off);
      if (lr == 0) redl[w * 32 + mi * 16 + lg * 4 + j] = ls;
    }
  __syncthreads();
  #pragma unroll
  for (int mi = 0; mi < 2; mi++)
    #pragma unroll
    for (int j = 0; j < 4; j++){
      int ql = mi * 16 + lg * 4 + j;
      float d = redl[ql];
      #pragma unroll
      for (int w2 = 1; w2 < 8; w2++) d += redl[w2 * 32 + ql];
      inv[mi][j] = 1.f / d;
    }

  // phase 4: PV (A-frags = P from LDS, B-frags = vt[h][d][k] contiguous)
  f32x4 o[2][4] = {};
  #pragma unroll
  for (int kc2 = 0; kc2 < 8; kc2++){
    u16x8 pa0 = *(u16x8*)&RP[(lr) * RPSTR + kb + kc2 * 32 + lg * 8];
    u16x8 pa1 = *(u16x8*)&RP[(16 + lr) * RPSTR + kb + kc2 * 32 + lg * 8];
    #pragma unroll
    for (int ni = 0; ni < 4; ni++){
      u16x8 vv = *(const u16x8*)(vt + (size_t)(h * DH + ni * 16 + lr) * LQ + kb + kc2 * 32 + lg * 8);
      o[0][ni] = MFMA(pa0, vv, o[0][ni]);
      o[1][ni] = MFMA(pa1, vv, o[1][ni]);
    }
  }

  // normalized map write as f32 (output 1)
  {
    int qrow = tid >> 4, cb = (tid & 15) * 8;
    float dsum = redl[qrow];
    #pragma unroll
    for (int w2 = 1; w2 < 8; w2++) dsum += redl[w2 * 32 + qrow];
    float invr = 1.f / dsum;
    float* mrow = map + (size_t)(h * LQ + q0 + qrow) * LQ;
    #pragma unroll
    for (int it = 0; it < 16; it++){
      int c = cb + it * 128;
      u16x8 pv = *(u16x8*)&RP[qrow * RPSTR + c];
      f32x4 o0, o1;
      #pragma unroll
      for (int j = 0; j < 4; j++){
        o0[j] = bf2f(pv[j]) * invr;
        o1[j] = bf2f(pv[4 + j]) * invr;
      }
      *(f32x4*)(mrow + c) = o0;
      *(f32x4*)(mrow + c + 4) = o1;
    }
  }
  __syncthreads();

  // cross-wave O reduction (overlays RP region)
  float* Op = (float*)smem;    // [8][32][64]
  #pragma unroll
  for (int mi = 0; mi < 2; mi++)
    #pragma unroll
    for (int ni = 0; ni < 4; ni++)
      #pragma unroll
      for (int j = 0; j < 4; j++)
        Op[(w * 32 + mi * 16 + lg * 4 + j) * 64 + ni * 16 + lr] = o[mi][ni][j] * inv[mi][j];
  __syncthreads();
  {
    int q = tid >> 4, dg = (tid & 15) * 4;
    f32x4 acc = {};
    #pragma unroll
    for (int w2 = 0; w2 < 8; w2++)
      acc += *(f32x4*)&Op[(w2 * 32 + q) * 64 + dg];
    *(f32x4*)(att + (size_t)(q0 + q) * DM + h * DH + dg) = acc;
  }
}

extern "C" void kernel_launch(void* const* d_in, const int* in_sizes, int n_in,
                              void* d_out, int out_size, void* d_ws, size_t ws_size,
                              hipStream_t stream){
  const float* v_in = (const float*)d_in[0];
  const float* k_in = (const float*)d_in[1];
  const float* q_in = (const float*)d_in[2];
  const int*   mask = (const int*)d_in[3];
  const float* Wq   = (const float*)d_in[4];
  const float* Wk   = (const float*)d_in[5];
  const float* Wv   = (const float*)d_in[6];
  const float* Wrk  = (const float*)d_in[7];
  const float* r_w  = (const float*)d_in[8];
  const float* r_r  = (const float*)d_in[9];
  const float* Wo   = (const float*)d_in[10];
  const float* bo   = (const float*)d_in[11];

  char* ws = (char*)d_ws;
  u16* qh = (u16*)(ws + 0);              // [12][2048][64] bf16
  u16* kh = (u16*)(ws + 3145728);
  u16* vh = (u16*)(ws + 6291456);
  u16* vt = (u16*)(ws + 9437184);        // [12][64][2048] bf16
  u16* rk = (u16*)(ws + 12582912);       // [12][4095][64] bf16
  float* pe = (float*)(ws + 18872832);   // [4095][768] f32
  float* att = (float*)(ws + 31452672);  // [2048][768] f32
  float* gamtab = (float*)(ws + 37744128);          // [2048][128] f32
  unsigned long long* gmax = (unsigned long long*)(ws + 38792704);

  float* out0 = (float*)d_out;                     // [2048][768] f32
  float* map  = out0 + (size_t)LQ * DM;            // [12][2048][2048] f32

  hipMemsetAsync(gmax, 0, 8, stream);
  gamma_probs_kernel<<<1024, 256, 0, stream>>>(gamtab, gmax);
  pe_kernel<<<(NR * DM + 255) / 256, 256, 0, stream>>>(gamtab, gmax, pe);

  gemm_kernel<<<dim3(32, 12), 256, 0, stream>>>(q_in, Wq, qh, nullptr, LQ, 0.125f, nullptr, 0);
  gemm_kernel<<<dim3(32, 12), 256, 0, stream>>>(k_in, Wk, kh, nullptr, LQ, 1.f, nullptr, 0);
  gemm_kernel<<<dim3(32, 12), 256, 0, stream>>>(v_in, Wv, vh, nullptr, LQ, 1.f, nullptr, 0);
  gemm_kernel<<<dim3(64, 12), 256, 0, stream>>>(pe, Wrk, rk, nullptr, NR, 1.f, nullptr, 0);
  transpose_v_kernel<<<dim3(32, 12), 256, 0, stream>>>(vh, vt);

  hipFuncSetAttribute((const void*)attn_kernel,
                      hipFuncAttributeMaxDynamicSharedMemorySize, SMEM_ATTN);
  attn_kernel<<<dim3(64, 12), 512, SMEM_ATTN, stream>>>(qh, kh, vt, rk, mask,
                                                        r_w, r_r, map, att);
  gemm_kernel<<<dim3(32, 12), 256, 0, stream>>>(att, Wo, nullptr, out0, LQ, 1.f, bo, 1);
}

// Round 8
// 323.225 us; speedup vs baseline: 1.0714x; 1.0714x over previous
//
#include <hip/hip_runtime.h>
#include <hip/hip_bf16.h>
#include <math.h>

typedef unsigned short u16;
typedef __bf16 bf16x8_t __attribute__((ext_vector_type(8)));
typedef u16 u16x8 __attribute__((ext_vector_type(8)));
typedef u16 u16x4 __attribute__((ext_vector_type(4)));
typedef float f32x4 __attribute__((ext_vector_type(4)));

#define NH 12
#define LQ 2048
#define DM 768
#define DH 64
#define NR 4095           // 2L-1
#define LN2F 0.6931471805599453f

__device__ __forceinline__ u16 f2bf(float f){
  unsigned x = __float_as_uint(f);
  return (u16)((x + 0x7fffu + ((x >> 16) & 1u)) >> 16);   // RTNE
}
__device__ __forceinline__ float bf2f(u16 u){ return __uint_as_float(((unsigned)u) << 16); }

__device__ __forceinline__ f32x4 MFMA(u16x8 a, u16x8 b, f32x4 c){
  return __builtin_amdgcn_mfma_f32_16x16x32_bf16(
      __builtin_bit_cast(bf16x8_t, a), __builtin_bit_cast(bf16x8_t, b), c, 0, 0, 0);
}

// ---------------- gamma pdf table (unnormalized) + global max ----------------
__global__ void gamma_probs_kernel(float* __restrict__ gamtab,
                                   unsigned long long* __restrict__ gmax){
  int idx = blockIdx.x * 256 + threadIdx.x;   // 2048*128
  int x = idx >> 7, f = idx & 127;
  double fp1 = (double)(f + 1);
  double conc = 4.0 * fp1 * fp1;
  double rate = 0.25 * fp1;
  double xd = (double)x;
  double xlogy = (x > 0) ? (conc - 1.0) * log(xd) : 0.0;
  double logp = xlogy - rate * xd - lgamma(conc) + conc * log(rate);
  double p = exp(logp);
  gamtab[idx] = (float)p;
  double m = p;
  #pragma unroll
  for (int off = 1; off < 64; off <<= 1) m = fmax(m, __shfl_xor(m, off));
  if ((threadIdx.x & 63) == 0)
    atomicMax(gmax, (unsigned long long)__double_as_longlong(m));
}

// ---------------- positional encodings pe[4095][768] ----------------
__global__ void pe_kernel(const float* __restrict__ gamtab,
                          const unsigned long long* __restrict__ gmax,
                          float* __restrict__ pe){
  int idx = blockIdx.x * 256 + threadIdx.x;
  if (idx >= NR * DM) return;
  int p = idx / DM;
  int c = idx - p * DM;
  int f = c & 127;
  int kind = c >> 7;
  int pos = p - (LQ - 1);
  int apos = pos < 0 ? -pos : pos;
  float sgn = (pos > 0) ? 1.f : ((pos < 0) ? -1.f : 0.f);
  float v;
  int grp = kind >> 1;
  if (grp == 0){
    float hl = exp2f(3.f + 8.f * (float)f / 127.f);
    v = expf(-(LN2F / hl) * (float)apos);
  } else if (grp == 1){
    float cw = exp2f((float)(f + 1)) - 1.f;
    v = (cw > (float)apos) ? 1.f : 0.f;
  } else {
    float gm = (float)__longlong_as_double((long long)*gmax);
    v = gamtab[apos * 128 + f] / gm;
  }
  if (kind & 1) v *= sgn;
  pe[idx] = v;
}

// ---------------- fused q/k/v projection GEMM (grid.z picks input) ----------
// z=0: qh bf16 head-major, *0.125; z=1: kh bf16 head-major; z=2: vt bf16 [h][d][k]
#define GSTR 56
__launch_bounds__(256)
__global__ void proj3_kernel(const float* __restrict__ q_in, const float* __restrict__ k_in,
                             const float* __restrict__ v_in,
                             const float* __restrict__ Wq, const float* __restrict__ Wk,
                             const float* __restrict__ Wv,
                             u16* __restrict__ qh, u16* __restrict__ kh,
                             u16* __restrict__ vt){
  __shared__ u16 At[64 * GSTR];
  __shared__ u16 Wt[64 * GSTR];
  const int z = blockIdx.z;
  const float* A = (z == 0) ? q_in : (z == 1) ? k_in : v_in;
  const float* W = (z == 0) ? Wq : (z == 1) ? Wk : Wv;
  const float scale = (z == 0) ? 0.125f : 1.f;
  const int m0 = blockIdx.x * 64, n0 = blockIdx.y * 64;
  const int tid = threadIdx.x;
  const int w = tid >> 6, l = tid & 63, lr = l & 15, lg = l >> 4;
  const int moff = (w & 1) * 32, noff = (w >> 1) * 32;
  f32x4 acc[2][2] = {};
  const int arow = tid >> 2, akg = (tid & 3) * 8;
  const int wn = tid & 63, wkg = (tid >> 6) * 8;
  for (int k0 = 0; k0 < DM; k0 += 32){
    u16x8 av;
    {
      const float* ap = A + (size_t)(m0 + arow) * DM + k0 + akg;
      #pragma unroll
      for (int j = 0; j < 8; j++) av[j] = f2bf(ap[j]);
    }
    *(u16x8*)&At[arow * GSTR + akg] = av;
    u16x8 wv;
    #pragma unroll
    for (int i = 0; i < 8; i++)
      wv[i] = f2bf(W[(size_t)(k0 + wkg + i) * DM + n0 + wn]);
    *(u16x8*)&Wt[wn * GSTR + wkg] = wv;
    __syncthreads();
    u16x8 af0 = *(u16x8*)&At[(moff + lr) * GSTR + lg * 8];
    u16x8 af1 = *(u16x8*)&At[(moff + 16 + lr) * GSTR + lg * 8];
    u16x8 bf0 = *(u16x8*)&Wt[(noff + lr) * GSTR + lg * 8];
    u16x8 bf1 = *(u16x8*)&Wt[(noff + 16 + lr) * GSTR + lg * 8];
    acc[0][0] = MFMA(af0, bf0, acc[0][0]);
    acc[0][1] = MFMA(af0, bf1, acc[0][1]);
    acc[1][0] = MFMA(af1, bf0, acc[1][0]);
    acc[1][1] = MFMA(af1, bf1, acc[1][1]);
    __syncthreads();
  }
  u16* outb = (z == 0) ? qh : kh;
  #pragma unroll
  for (int mi = 0; mi < 2; mi++)
    #pragma unroll
    for (int ni = 0; ni < 2; ni++){
      if (z < 2){
        #pragma unroll
        for (int j = 0; j < 4; j++){
          int m = m0 + moff + mi * 16 + lg * 4 + j;
          int n = n0 + noff + ni * 16 + lr;
          outb[((size_t)(n >> 6) * LQ + m) * DH + (n & 63)] = f2bf(acc[mi][ni][j] * scale);
        }
      } else {
        // transposed: vt[(h*64 + d)*LQ + m], 4 consecutive m per thread
        int m = m0 + moff + mi * 16 + lg * 4;
        int n = n0 + noff + ni * 16 + lr;
        u16x4 ov;
        #pragma unroll
        for (int j = 0; j < 4; j++) ov[j] = f2bf(acc[mi][ni][j]);
        *(u16x4*)(vt + ((size_t)(n >> 6) * DH + (n & 63)) * LQ + m) = ov;
      }
    }
}

// ---------------- generic bf16-MFMA GEMM (rk + out-proj) ----------------
// mode 0: outb bf16 head-major [(n>>6)*M + m][n&63]
// mode 1: outf f32 flat [m*768+n] + bias
__launch_bounds__(256)
__global__ void gemm_kernel(const float* __restrict__ A, const float* __restrict__ W,
                            u16* __restrict__ outb, float* __restrict__ outf,
                            int M, float scale,
                            const float* __restrict__ bias, int mode){
  __shared__ u16 At[64 * GSTR];
  __shared__ u16 Wt[64 * GSTR];
  const int m0 = blockIdx.x * 64, n0 = blockIdx.y * 64;
  const int tid = threadIdx.x;
  const int w = tid >> 6, l = tid & 63, lr = l & 15, lg = l >> 4;
  const int moff = (w & 1) * 32, noff = (w >> 1) * 32;
  f32x4 acc[2][2] = {};
  const int arow = tid >> 2, akg = (tid & 3) * 8;
  const int wn = tid & 63, wkg = (tid >> 6) * 8;
  for (int k0 = 0; k0 < DM; k0 += 32){
    u16x8 av;
    if (m0 + arow < M){
      const float* ap = A + (size_t)(m0 + arow) * DM + k0 + akg;
      #pragma unroll
      for (int j = 0; j < 8; j++) av[j] = f2bf(ap[j]);
    } else {
      #pragma unroll
      for (int j = 0; j < 8; j++) av[j] = 0;
    }
    *(u16x8*)&At[arow * GSTR + akg] = av;
    u16x8 wv;
    #pragma unroll
    for (int i = 0; i < 8; i++)
      wv[i] = f2bf(W[(size_t)(k0 + wkg + i) * DM + n0 + wn]);
    *(u16x8*)&Wt[wn * GSTR + wkg] = wv;
    __syncthreads();
    u16x8 af0 = *(u16x8*)&At[(moff + lr) * GSTR + lg * 8];
    u16x8 af1 = *(u16x8*)&At[(moff + 16 + lr) * GSTR + lg * 8];
    u16x8 bf0 = *(u16x8*)&Wt[(noff + lr) * GSTR + lg * 8];
    u16x8 bf1 = *(u16x8*)&Wt[(noff + 16 + lr) * GSTR + lg * 8];
    acc[0][0] = MFMA(af0, bf0, acc[0][0]);
    acc[0][1] = MFMA(af0, bf1, acc[0][1]);
    acc[1][0] = MFMA(af1, bf0, acc[1][0]);
    acc[1][1] = MFMA(af1, bf1, acc[1][1]);
    __syncthreads();
  }
  #pragma unroll
  for (int mi = 0; mi < 2; mi++)
    #pragma unroll
    for (int ni = 0; ni < 2; ni++)
      #pragma unroll
      for (int j = 0; j < 4; j++){
        int m = m0 + moff + mi * 16 + lg * 4 + j;
        int n = n0 + noff + ni * 16 + lr;
        if (m < M){
          float v = acc[mi][ni][j] * scale;
          if (mode == 1){
            outf[(size_t)m * DM + n] = v + bias[n];
          } else {
            outb[((size_t)(n >> 6) * M + m) * DH + (n & 63)] = f2bf(v);
          }
        }
      }
}

// ---------------- fused rel-pos attention, QBLK=16 ----------------
// One WG = 1 head x 16 q-rows, 8 waves; wave w owns k-slice [w*256, w*256+256)
// and band slice [w*272, w*272+272). LDS band RP[16][2184] bf16; S in regs.
// ~71 KB LDS -> 2 WGs/CU (16 waves).
#define QB 16
#define RPSTR 2184
#define SMEM_ATTN (QB * RPSTR * 2 + 1024)
__launch_bounds__(512, 4)
__global__ void attn_kernel(const u16* __restrict__ qh, const u16* __restrict__ kh,
                            const u16* __restrict__ vt, const u16* __restrict__ rk,
                            const int* __restrict__ mask,
                            const float* __restrict__ r_w, const float* __restrict__ r_r,
                            float* __restrict__ map, float* __restrict__ att){
  extern __shared__ char smem[];
  u16* RP = (u16*)smem;
  float* redm = (float*)(smem + QB * RPSTR * 2);   // [8][16]
  float* redl = redm + 128;                        // [8][16]
  const int h = blockIdx.y, q0 = blockIdx.x * QB;
  const int tid = threadIdx.x, w = tid >> 6, l = tid & 63, lr = l & 15, lg = l >> 4;
  const int roff = (LQ - 1) - q0 - (QB - 1);       // 2032 - q0

  // phase 0: A fragments a1=(qh+r_w), a2=(qh+r_r)  (qh pre-scaled by 1/8)
  u16x8 a1[2], a2[2];
  #pragma unroll
  for (int kc = 0; kc < 2; kc++){
    u16x8 qv = *(const u16x8*)(qh + (size_t)(h * LQ + q0 + lr) * DH + kc * 32 + lg * 8);
    #pragma unroll
    for (int j = 0; j < 8; j++){
      int d = kc * 32 + lg * 8 + j;
      float f = bf2f(qv[j]);
      a1[kc][j] = f2bf(f + r_w[h * DH + d]);
      a2[kc][j] = f2bf(f + r_r[h * DH + d]);
    }
  }

  // phase 1: rel band R[q][j] = a2[q] . rk[roff + j], wave slice 17 tiles
  const int jb = w * 272;
  #pragma unroll 4
  for (int jt = 0; jt < 17; jt++){
    f32x4 racc = {};
    #pragma unroll
    for (int kc = 0; kc < 2; kc++){
      int r = roff + jb + jt * 16 + lr;
      if (r > NR - 1) r = NR - 1;     // clamped tail never gathered
      u16x8 bv = *(const u16x8*)(rk + (size_t)(h * NR + r) * DH + kc * 32 + lg * 8);
      racc = MFMA(a2[kc], bv, racc);
    }
    #pragma unroll
    for (int j = 0; j < 4; j++)
      RP[(lg * 4 + j) * RPSTR + jb + jt * 16 + lr] = f2bf(racc[j]);
  }
  __syncthreads();

  // phase 2: content logits + gathered rel (j = k + 15 - ql) + mask
  const int kb = w * 256;
  f32x4 s[16] = {};
  #pragma unroll
  for (int nt = 0; nt < 16; nt++){
    #pragma unroll
    for (int kc = 0; kc < 2; kc++){
      u16x8 bv = *(const u16x8*)(kh + (size_t)(h * LQ + kb + nt * 16 + lr) * DH + kc * 32 + lg * 8);
      s[nt] = MFMA(a1[kc], bv, s[nt]);
    }
  }
  #pragma unroll
  for (int nt = 0; nt < 16; nt++){
    int kg = kb + nt * 16 + lr;
    int mv = mask[kg];
    #pragma unroll
    for (int j = 0; j < 4; j++){
      int ql = lg * 4 + j;
      float sv = s[nt][j] + bf2f(RP[ql * RPSTR + kg + (QB - 1) - ql]);
      s[nt][j] = (mv == 1) ? -10000.f : sv;
    }
  }

  // phase 3: exact softmax (16-lane col groups, cross-wave via LDS)
  float fm[4], inv[4], lsum[4];
  #pragma unroll
  for (int j = 0; j < 4; j++){
    float mx = -3.0e38f;
    #pragma unroll
    for (int nt = 0; nt < 16; nt++) mx = fmaxf(mx, s[nt][j]);
    #pragma unroll
    for (int off = 1; off < 16; off <<= 1) mx = fmaxf(mx, __shfl_xor(mx, off));
    if (lr == 0) redm[w * QB + lg * 4 + j] = mx;
  }
  __syncthreads();
  #pragma unroll
  for (int j = 0; j < 4; j++){
    int ql = lg * 4 + j;
    float mx = redm[ql];
    #pragma unroll
    for (int w2 = 1; w2 < 8; w2++) mx = fmaxf(mx, redm[w2 * QB + ql]);
    fm[j] = mx;
    lsum[j] = 0.f;
  }
  #pragma unroll
  for (int nt = 0; nt < 16; nt++)
    #pragma unroll
    for (int j = 0; j < 4; j++){
      float p = __expf(s[nt][j] - fm[j]);
      lsum[j] += p;
      RP[(lg * 4 + j) * RPSTR + kb + nt * 16 + lr] = f2bf(p);   // P overwrites R
    }
  #pragma unroll
  for (int j = 0; j < 4; j++){
    float ls = lsum[j];
    #pragma unroll
    for (int off = 1; off < 16; off <<= 1) ls += __shfl_xor(ls, off);
    if (lr == 0) redl[w * QB + lg * 4 + j] = ls;
  }
  __syncthreads();
  #pragma unroll
  for (int j = 0; j < 4; j++){
    int ql = lg * 4 + j;
    float d = redl[ql];
    #pragma unroll
    for (int w2 = 1; w2 < 8; w2++) d += redl[w2 * QB + ql];
    inv[j] = 1.f / d;
  }

  // phase 4: PV (A-frags = P rows lr, B-frags = vt[h][d][k] contiguous)
  f32x4 o[4] = {};
  #pragma unroll
  for (int kc2 = 0; kc2 < 8; kc2++){
    u16x8 pa = *(u16x8*)&RP[lr * RPSTR + kb + kc2 * 32 + lg * 8];
    #pragma unroll
    for (int ni = 0; ni < 4; ni++){
      u16x8 vv = *(const u16x8*)(vt + (size_t)(h * DH + ni * 16 + lr) * LQ + kb + kc2 * 32 + lg * 8);
      o[ni] = MFMA(pa, vv, o[ni]);
    }
  }

  // normalized map write as f32 (output 1): 32 threads per q-row
  {
    int qrow = tid >> 5, cb = (tid & 31) * 8;
    float dsum = redl[qrow];
    #pragma unroll
    for (int w2 = 1; w2 < 8; w2++) dsum += redl[w2 * QB + qrow];
    float invr = 1.f / dsum;
    float* mrow = map + (size_t)(h * LQ + q0 + qrow) * LQ;
    #pragma unroll
    for (int it = 0; it < 8; it++){
      int c = cb + it * 256;
      u16x8 pv = *(u16x8*)&RP[qrow * RPSTR + c];
      f32x4 o0, o1;
      #pragma unroll
      for (int j = 0; j < 4; j++){
        o0[j] = bf2f(pv[j]) * invr;
        o1[j] = bf2f(pv[4 + j]) * invr;
      }
      *(f32x4*)(mrow + c) = o0;
      *(f32x4*)(mrow + c + 4) = o1;
    }
  }
  __syncthreads();

  // cross-wave O reduction (overlays RP region)
  float* Op = (float*)smem;    // [8][16][64]
  #pragma unroll
  for (int ni = 0; ni < 4; ni++)
    #pragma unroll
    for (int j = 0; j < 4; j++)
      Op[(w * QB + lg * 4 + j) * 64 + ni * 16 + lr] = o[ni][j] * inv[j];
  __syncthreads();
  {
    int q = tid >> 5, dg = (tid & 31) * 2;
    float acc0 = 0.f, acc1 = 0.f;
    #pragma unroll
    for (int w2 = 0; w2 < 8; w2++){
      acc0 += Op[(w2 * QB + q) * 64 + dg];
      acc1 += Op[(w2 * QB + q) * 64 + dg + 1];
    }
    float* ap = att + (size_t)(q0 + q) * DM + h * DH + dg;
    ap[0] = acc0;
    ap[1] = acc1;
  }
}

extern "C" void kernel_launch(void* const* d_in, const int* in_sizes, int n_in,
                              void* d_out, int out_size, void* d_ws, size_t ws_size,
                              hipStream_t stream){
  const float* v_in = (const float*)d_in[0];
  const float* k_in = (const float*)d_in[1];
  const float* q_in = (const float*)d_in[2];
  const int*   mask = (const int*)d_in[3];
  const float* Wq   = (const float*)d_in[4];
  const float* Wk   = (const float*)d_in[5];
  const float* Wv   = (const float*)d_in[6];
  const float* Wrk  = (const float*)d_in[7];
  const float* r_w  = (const float*)d_in[8];
  const float* r_r  = (const float*)d_in[9];
  const float* Wo   = (const float*)d_in[10];
  const float* bo   = (const float*)d_in[11];

  char* ws = (char*)d_ws;
  u16* qh = (u16*)(ws + 0);              // [12][2048][64] bf16
  u16* kh = (u16*)(ws + 3145728);
  u16* vt = (u16*)(ws + 6291456);        // [12][64][2048] bf16
  u16* rk = (u16*)(ws + 9437184);        // [12][4095][64] bf16
  float* pe = (float*)(ws + 15727104);   // [4095][768] f32
  float* att = (float*)(ws + 28306944);  // [2048][768] f32
  float* gamtab = (float*)(ws + 34598400);           // [2048][128] f32
  unsigned long long* gmax = (unsigned long long*)(ws + 35646976);

  float* out0 = (float*)d_out;                     // [2048][768] f32
  float* map  = out0 + (size_t)LQ * DM;            // [12][2048][2048] f32

  hipMemsetAsync(gmax, 0, 8, stream);
  gamma_probs_kernel<<<1024, 256, 0, stream>>>(gamtab, gmax);
  pe_kernel<<<(NR * DM + 255) / 256, 256, 0, stream>>>(gamtab, gmax, pe);

  proj3_kernel<<<dim3(32, 12, 3), 256, 0, stream>>>(q_in, k_in, v_in, Wq, Wk, Wv,
                                                    qh, kh, vt);
  gemm_kernel<<<dim3(64, 12), 256, 0, stream>>>(pe, Wrk, rk, nullptr, NR, 1.f, nullptr, 0);

  hipFuncSetAttribute((const void*)attn_kernel,
                      hipFuncAttributeMaxDynamicSharedMemorySize, SMEM_ATTN);
  attn_kernel<<<dim3(LQ / QB, 12), 512, SMEM_ATTN, stream>>>(qh, kh, vt, rk, mask,
                                                             r_w, r_r, map, att);
  gemm_kernel<<<dim3(32, 12), 256, 0, stream>>>(att, Wo, nullptr, out0, LQ, 1.f, bo, 1);
}